// Round 4
// baseline (627.380 us; speedup 1.0000x reference)
//
#include <hip/hip_runtime.h>

#define BATCH 524288
#define NOISE_STD 0.4466835921509630f
#define INV_SQRT2 0.7071067811865476f

__device__ __forceinline__ float eluf(float x) {
    return x > 0.0f ? x : __expf(x) - 1.0f;
}

// tanh(x) = 1 - 2/(exp(2x)+1). No clamp needed: exp->inf gives 1-2/inf = 1,
// exp->0 gives 1-2/1 = -1. (clamp removal saves 2 VALU ops per tanh)
__device__ __forceinline__ float ftanh(float x) {
    float t = __expf(2.0f * x);
    return 1.0f - __fdividef(2.0f, t + 1.0f);
}

// __launch_bounds__(256, 1): min 1 wave/EU releases the VGPR cap (R2 showed
// VGPR_Count=56 < ~100-float live set -> spill/remat inflated VALU time 3.5x)
__global__ __launch_bounds__(256, 1) void enc_kernel(
    const float* __restrict__ x,
    const float* __restrict__ w1, const float* __restrict__ b1,
    const float* __restrict__ w2, const float* __restrict__ b2,
    const float* __restrict__ cw1, const float* __restrict__ cb1,
    const float* __restrict__ cw2, const float* __restrict__ cb2,
    const float* __restrict__ cw3, const float* __restrict__ cb3,
    const float* __restrict__ cw4, const float* __restrict__ cb4,
    const float* __restrict__ w3, const float* __restrict__ b3,
    const float* __restrict__ w4, const float* __restrict__ b4,
    float* __restrict__ g_out, float* __restrict__ partials)
{
    const int row = blockIdx.x * 256 + threadIdx.x;

    float v[16];
    {
        const float4* xp = (const float4*)(x + (size_t)row * 16);
        float4 a0 = xp[0], a1 = xp[1], a2 = xp[2], a3 = xp[3];
        v[0]=a0.x; v[1]=a0.y; v[2]=a0.z; v[3]=a0.w;
        v[4]=a1.x; v[5]=a1.y; v[6]=a1.z; v[7]=a1.w;
        v[8]=a2.x; v[9]=a2.y; v[10]=a2.z; v[11]=a2.w;
        v[12]=a3.x; v[13]=a3.y; v[14]=a3.z; v[15]=a3.w;
    }

    // dense1: (16) @ (16,16) + b1, ELU
    float h1[16];
#pragma unroll
    for (int j = 0; j < 16; ++j) h1[j] = b1[j];
#pragma unroll
    for (int i = 0; i < 16; ++i) {
        float vi = v[i];
#pragma unroll
        for (int j = 0; j < 16; ++j) h1[j] += vi * w1[i*16+j];
    }
#pragma unroll
    for (int j = 0; j < 16; ++j) h1[j] = eluf(h1[j]);

    // dense2: (16) @ (16,16) + b2, ELU
    float h2[16];
#pragma unroll
    for (int j = 0; j < 16; ++j) h2[j] = b2[j];
#pragma unroll
    for (int i = 0; i < 16; ++i) {
        float vi = h1[i];
#pragma unroll
        for (int j = 0; j < 16; ++j) h2[j] += vi * w2[i*16+j];
    }
#pragma unroll
    for (int j = 0; j < 16; ++j) h2[j] = eluf(h2[j]);

    // conv1 (1ch->8ch, k=2, s=1) fused with conv2 (8->8, k=4, s=2) via rolling window.
    // conv2 uses conv1 positions 0..13 only (position 14 is dead in the reference).
    float win[8][4];   // conv1 outputs at positions 2p .. 2p+3
#pragma unroll
    for (int k = 0; k < 4; ++k)
#pragma unroll
        for (int ic = 0; ic < 8; ++ic)
            win[ic][k] = ftanh(cb1[ic] + cw1[ic*2]*h2[k] + cw1[ic*2+1]*h2[k+1]);

    float o2[8][6];
#pragma unroll
    for (int p = 0; p < 6; ++p) {
#pragma unroll
        for (int oc = 0; oc < 8; ++oc) {
            float acc = cb2[oc];
#pragma unroll
            for (int ic = 0; ic < 8; ++ic)
#pragma unroll
                for (int k = 0; k < 4; ++k)
                    acc += cw2[oc*32+ic*4+k] * win[ic][k];
            o2[oc][p] = ftanh(acc);
        }
        if (p < 5) {
#pragma unroll
            for (int ic = 0; ic < 8; ++ic) {
                win[ic][0] = win[ic][2];
                win[ic][1] = win[ic][3];
                win[ic][2] = ftanh(cb1[ic] + cw1[ic*2]*h2[2*p+4] + cw1[ic*2+1]*h2[2*p+5]);
                win[ic][3] = ftanh(cb1[ic] + cw1[ic*2]*h2[2*p+5] + cw1[ic*2+1]*h2[2*p+6]);
            }
        }
    }

    // conv3 (8->8, k=2, s=1): 6 -> 5
    float o3[8][5];
#pragma unroll
    for (int p = 0; p < 5; ++p)
#pragma unroll
        for (int oc = 0; oc < 8; ++oc) {
            float acc = cb3[oc];
#pragma unroll
            for (int ic = 0; ic < 8; ++ic)
                acc += cw3[oc*16+ic*2]*o2[ic][p] + cw3[oc*16+ic*2+1]*o2[ic][p+1];
            o3[oc][p] = ftanh(acc);
        }

    // conv4 (8->8, k=2, s=1): 5 -> 4
    float o4[8][4];
#pragma unroll
    for (int p = 0; p < 4; ++p)
#pragma unroll
        for (int oc = 0; oc < 8; ++oc) {
            float acc = cb4[oc];
#pragma unroll
            for (int ic = 0; ic < 8; ++ic)
                acc += cw4[oc*16+ic*2]*o3[ic][p] + cw4[oc*16+ic*2+1]*o3[ic][p+1];
            o4[oc][p] = ftanh(acc);
        }

    // flatten (ch-major) -> dense w3 (32,32), tanh
    float t3[32];
#pragma unroll
    for (int j = 0; j < 32; ++j) t3[j] = b3[j];
#pragma unroll
    for (int oc = 0; oc < 8; ++oc)
#pragma unroll
        for (int p = 0; p < 4; ++p) {
            float fv = o4[oc][p];
            const int i = oc*4 + p;
#pragma unroll
            for (int j = 0; j < 32; ++j) t3[j] += fv * w3[i*32+j];
        }
#pragma unroll
    for (int j = 0; j < 32; ++j) t3[j] = ftanh(t3[j]);

    // dense w4 (32,16) -> pre-norm code g
    float g[16];
#pragma unroll
    for (int j = 0; j < 16; ++j) g[j] = b4[j];
#pragma unroll
    for (int i = 0; i < 32; ++i) {
        float fv = t3[i];
#pragma unroll
        for (int j = 0; j < 16; ++j) g[j] += fv * w4[i*16+j];
    }

    {
        float4* gp = (float4*)(g_out + (size_t)row * 16);
        gp[0] = make_float4(g[0],g[1],g[2],g[3]);
        gp[1] = make_float4(g[4],g[5],g[6],g[7]);
        gp[2] = make_float4(g[8],g[9],g[10],g[11]);
        gp[3] = make_float4(g[12],g[13],g[14],g[15]);
    }

    // per-block column sums and sumsq (deterministic, no atomics)
    __shared__ float red[4][32];
    const int lane = threadIdx.x & 63;
    const int wid = threadIdx.x >> 6;
#pragma unroll
    for (int c = 0; c < 16; ++c) {
        float s = g[c];
        float q = g[c]*g[c];
#pragma unroll
        for (int off = 32; off > 0; off >>= 1) {
            s += __shfl_xor(s, off);
            q += __shfl_xor(q, off);
        }
        if (lane == c)      red[wid][c]      = s;
        if (lane == 16 + c) red[wid][16 + c] = q;
    }
    __syncthreads();
    if (threadIdx.x < 32) {
        float t = red[0][threadIdx.x] + red[1][threadIdx.x]
                + red[2][threadIdx.x] + red[3][threadIdx.x];
        partials[blockIdx.x * 32 + threadIdx.x] = t;
    }
}

__global__ void stat_kernel(const float* __restrict__ partials,
                            float* __restrict__ muinv, int nblocks)
{
    __shared__ float lds[256];
    const int t = threadIdx.x;
    const int c = t & 31, chunk = t >> 5;   // 8 chunks x 32 cols
    // 4 independent accumulators to keep multiple loads in flight
    float s0 = 0.0f, s1 = 0.0f, s2 = 0.0f, s3 = 0.0f;
    for (int b = chunk; b + 24 < nblocks; b += 32) {
        s0 += partials[(b     )*32 + c];
        s1 += partials[(b +  8)*32 + c];
        s2 += partials[(b + 16)*32 + c];
        s3 += partials[(b + 24)*32 + c];
    }
    lds[t] = (s0 + s1) + (s2 + s3);
    __syncthreads();
    if (t < 32) {
        float tot = 0.0f;
#pragma unroll
        for (int k = 0; k < 8; ++k) tot += lds[k*32 + t];
        lds[t] = tot;
    }
    __syncthreads();
    if (t < 16) {
        float mu  = lds[t] * (1.0f / (float)BATCH);
        float var = lds[16 + t] * (1.0f / (float)BATCH) - mu * mu;
        muinv[t]      = mu;
        muinv[16 + t] = rsqrtf(var + 1e-5f);
    }
}

__global__ __launch_bounds__(256, 1) void dec_kernel(
    const float* __restrict__ g_in,
    const float* __restrict__ noise,
    const float* __restrict__ fading,
    const float* __restrict__ muinv,
    const float* __restrict__ dw1, const float* __restrict__ db1,
    const float* __restrict__ dw2, const float* __restrict__ db2,
    float* __restrict__ out)
{
    const int row = blockIdx.x * 256 + threadIdx.x;

    float enc[16];
    {
        const float4* gp = (const float4*)(g_in + (size_t)row * 16);
        float4 a0 = gp[0], a1 = gp[1], a2 = gp[2], a3 = gp[3];
        float g[16] = {a0.x,a0.y,a0.z,a0.w, a1.x,a1.y,a1.z,a1.w,
                       a2.x,a2.y,a2.z,a2.w, a3.x,a3.y,a3.z,a3.w};
#pragma unroll
        for (int c = 0; c < 16; ++c)
            enc[c] = (g[c] - muinv[c]) * muinv[16 + c];
    }

    float hr[3], hi[3];
    {
        const float2* fd = (const float2*)(fading + (size_t)row * 6);
        float2 f0 = fd[0], f1 = fd[1], f2 = fd[2];
        hr[0] = f0.x * INV_SQRT2; hi[0] = f0.y * INV_SQRT2;
        hr[1] = f1.x * INV_SQRT2; hi[1] = f1.y * INV_SQRT2;
        hr[2] = f2.x * INV_SQRT2; hi[2] = f2.y * INV_SQRT2;
    }

    // causal 3-tap complex conv: out[n] = sum_t hc[t] * xc[n-t], xc[<0]=0
    float cvec[16];
    {
        const float4* npz = (const float4*)(noise + (size_t)row * 16);
        float4 n0 = npz[0], n1 = npz[1], n2 = npz[2], n3 = npz[3];
        float nz[16] = {n0.x,n0.y,n0.z,n0.w, n1.x,n1.y,n1.z,n1.w,
                        n2.x,n2.y,n2.z,n2.w, n3.x,n3.y,n3.z,n3.w};
#pragma unroll
        for (int n = 0; n < 8; ++n) {
            float sr = 0.0f, si = 0.0f;
#pragma unroll
            for (int t = 0; t < 3; ++t) {
                if (n - t >= 0) {
                    float xr = enc[2*(n-t)], xi = enc[2*(n-t)+1];
                    sr += hr[t]*xr - hi[t]*xi;
                    si += hr[t]*xi + hi[t]*xr;
                }
            }
            cvec[2*n]   = sr + nz[2*n]   * NOISE_STD;
            cvec[2*n+1] = si + nz[2*n+1] * NOISE_STD;
        }
    }

    // decoder dense1: (16) @ (16,32) + db1, ELU
    float d[32];
#pragma unroll
    for (int j = 0; j < 32; ++j) d[j] = db1[j];
#pragma unroll
    for (int i = 0; i < 16; ++i) {
        float ci = cvec[i];
#pragma unroll
        for (int j = 0; j < 32; ++j) d[j] += ci * dw1[i*32+j];
    }
#pragma unroll
    for (int j = 0; j < 32; ++j) d[j] = eluf(d[j]);

    // decoder dense2: (32) @ (32,16) + db2
    float o[16];
#pragma unroll
    for (int j = 0; j < 16; ++j) o[j] = db2[j];
#pragma unroll
    for (int i = 0; i < 32; ++i) {
        float di = d[i];
#pragma unroll
        for (int j = 0; j < 16; ++j) o[j] += di * dw2[i*16+j];
    }

    float4* op = (float4*)(out + (size_t)row * 16);
    op[0] = make_float4(o[0],o[1],o[2],o[3]);
    op[1] = make_float4(o[4],o[5],o[6],o[7]);
    op[2] = make_float4(o[8],o[9],o[10],o[11]);
    op[3] = make_float4(o[12],o[13],o[14],o[15]);
}

extern "C" void kernel_launch(void* const* d_in, const int* in_sizes, int n_in,
                              void* d_out, int out_size, void* d_ws, size_t ws_size,
                              hipStream_t stream) {
    (void)in_sizes; (void)n_in; (void)out_size; (void)ws_size;

    const float* x      = (const float*)d_in[0];
    const float* noise  = (const float*)d_in[1];
    const float* fading = (const float*)d_in[2];
    const float* w1  = (const float*)d_in[3];
    const float* b1  = (const float*)d_in[4];
    const float* w2  = (const float*)d_in[5];
    const float* b2  = (const float*)d_in[6];
    const float* cw1 = (const float*)d_in[7];
    const float* cb1 = (const float*)d_in[8];
    const float* cw2 = (const float*)d_in[9];
    const float* cb2 = (const float*)d_in[10];
    const float* cw3 = (const float*)d_in[11];
    const float* cb3 = (const float*)d_in[12];
    const float* cw4 = (const float*)d_in[13];
    const float* cb4 = (const float*)d_in[14];
    const float* w3  = (const float*)d_in[15];
    const float* b3  = (const float*)d_in[16];
    const float* w4  = (const float*)d_in[17];
    const float* b4  = (const float*)d_in[18];
    const float* dw1 = (const float*)d_in[19];
    const float* db1 = (const float*)d_in[20];
    const float* dw2 = (const float*)d_in[21];
    const float* db2 = (const float*)d_in[22];
    float* outp = (float*)d_out;

    float* ws       = (float*)d_ws;
    float* muinv    = ws;                 // 32 floats
    float* partials = ws + 32;            // 2048*32 floats
    float* g        = ws + 32 + 2048*32;  // BATCH*16 floats

    const int nb = BATCH / 256;  // 2048

    enc_kernel<<<nb, 256, 0, stream>>>(x, w1,b1, w2,b2, cw1,cb1, cw2,cb2,
                                       cw3,cb3, cw4,cb4, w3,b3, w4,b4,
                                       g, partials);
    stat_kernel<<<1, 256, 0, stream>>>(partials, muinv, nb);
    dec_kernel<<<nb, 256, 0, stream>>>(g, noise, fading, muinv,
                                       dw1,db1, dw2,db2, outp);
}

// Round 7
// 433.000 us; speedup vs baseline: 1.4489x; 1.4489x over previous
//
#include <hip/hip_runtime.h>

#define BATCH 524288
#define NOISE_STD 0.4466835921509630f
#define INV_SQRT2 0.7071067811865476f

__device__ __forceinline__ float eluf(float x) {
    return x > 0.0f ? x : __expf(x) - 1.0f;
}

// tanh(x) = 1 - 2/(exp(2x)+1); exp->inf gives 1, exp->0 gives -1 (no clamp needed)
__device__ __forceinline__ float ftanh(float x) {
    float t = __expf(2.0f * x);
    return 1.0f - __fdividef(2.0f, t + 1.0f);
}

// waves_per_eu(2,2): cap the scheduler's target occupancy at 2 waves/EU so the
// register budget is 256 VGPRs (R2/R4 showed the default 8-wave target caps at
// 56-64 VGPR and remat/serializes the ~135-float live set).
__global__ __attribute__((amdgpu_flat_work_group_size(256,256), amdgpu_waves_per_eu(2,2)))
void enc_kernel(
    const float* __restrict__ x,
    const float* __restrict__ w1, const float* __restrict__ b1,
    const float* __restrict__ w2, const float* __restrict__ b2,
    const float* __restrict__ cw1, const float* __restrict__ cb1,
    const float* __restrict__ cw2, const float* __restrict__ cb2,
    const float* __restrict__ cw3, const float* __restrict__ cb3,
    const float* __restrict__ cw4, const float* __restrict__ cb4,
    const float* __restrict__ w3, const float* __restrict__ b3,
    const float* __restrict__ w4, const float* __restrict__ b4,
    float* __restrict__ g_out, float* __restrict__ partials)
{
    __shared__ float h2s[256][17];   // padded: stride 17 floats -> conflict-free
    __shared__ float red[4][32];

    const int tid = threadIdx.x;
    const int row = blockIdx.x * 256 + tid;

    float v[16];
    {
        const float4* xp = (const float4*)(x + (size_t)row * 16);
        float4 a0 = xp[0], a1 = xp[1], a2 = xp[2], a3 = xp[3];
        v[0]=a0.x; v[1]=a0.y; v[2]=a0.z; v[3]=a0.w;
        v[4]=a1.x; v[5]=a1.y; v[6]=a1.z; v[7]=a1.w;
        v[8]=a2.x; v[9]=a2.y; v[10]=a2.z; v[11]=a2.w;
        v[12]=a3.x; v[13]=a3.y; v[14]=a3.z; v[15]=a3.w;
    }

    // dense1 + ELU
    float h1[16];
#pragma unroll
    for (int j = 0; j < 16; ++j) h1[j] = b1[j];
#pragma unroll
    for (int i = 0; i < 16; ++i) {
        float vi = v[i];
#pragma unroll
        for (int j = 0; j < 16; ++j) h1[j] += vi * w1[i*16+j];
    }
#pragma unroll
    for (int j = 0; j < 16; ++j) h1[j] = eluf(h1[j]);

    // dense2 + ELU -> h2 (regs) + LDS copy for runtime indexing in the conv pipeline
    float h2[16];
#pragma unroll
    for (int j = 0; j < 16; ++j) h2[j] = b2[j];
#pragma unroll
    for (int i = 0; i < 16; ++i) {
        float vi = h1[i];
#pragma unroll
        for (int j = 0; j < 16; ++j) h2[j] += vi * w2[i*16+j];
    }
#pragma unroll
    for (int j = 0; j < 16; ++j) {
        h2[j] = eluf(h2[j]);
        h2s[tid][j] = h2[j];
    }

    // ---- conv pipeline: 3 rolled iterations, 2 conv2 positions each ----
    // c1[q] = tanh(cb1 + cw1[ic][0]*h2[q] + cw1[ic][1]*h2[q+1]), q=0..13 used
    // o2[p] = tanh(conv2 over c1[2p..2p+3]), p=0..5
    // o3[q] = tanh(conv3 over o2[q..q+1]),  q=0..4
    // o4[r] = tanh(conv4 over o3[r..r+1]),  r=0..3 -> fold into t3 (i = oc*4+r)
    float cA[8], cB[8];          // carry: c1[4pp], c1[4pp+1]
#pragma unroll
    for (int ic = 0; ic < 8; ++ic) {
        cA[ic] = ftanh(cb1[ic] + cw1[ic*2]*h2[0] + cw1[ic*2+1]*h2[1]);
        cB[ic] = ftanh(cb1[ic] + cw1[ic*2]*h2[1] + cw1[ic*2+1]*h2[2]);
    }
    float o2p[8], o3p[8];        // o2[2pp-1], o3[2pp-2] carries
#pragma unroll
    for (int ic = 0; ic < 8; ++ic) { o2p[ic] = 0.0f; o3p[ic] = 0.0f; }

    float t3[32];
#pragma unroll
    for (int j = 0; j < 32; ++j) t3[j] = b3[j];

#pragma unroll 1
    for (int pp = 0; pp < 3; ++pp) {
        const float* hrow = &h2s[tid][0];
        const int b4i = 4*pp;
        float e2 = hrow[b4i+2], e3 = hrow[b4i+3], e4 = hrow[b4i+4],
              e5 = hrow[b4i+5], e6 = hrow[b4i+6];

        // 4 new conv1 positions: c1[4pp+2 .. 4pp+5]
        float n0[8], n1[8], n2[8], n3[8];
#pragma unroll
        for (int ic = 0; ic < 8; ++ic) {
            float wa = cw1[ic*2], wb = cw1[ic*2+1], bb = cb1[ic];
            n0[ic] = ftanh(bb + wa*e2 + wb*e3);
            n1[ic] = ftanh(bb + wa*e3 + wb*e4);
            n2[ic] = ftanh(bb + wa*e4 + wb*e5);
            n3[ic] = ftanh(bb + wa*e5 + wb*e6);
        }

        // o2[2pp] from (cA,cB,n0,n1); o2[2pp+1] from (n0..n3)
        float oA[8], oB[8];
#pragma unroll
        for (int oc = 0; oc < 8; ++oc) {
            float accA = cb2[oc], accB = cb2[oc];
#pragma unroll
            for (int ic = 0; ic < 8; ++ic) {
                const float* w = &cw2[oc*32 + ic*4];
                accA += w[0]*cA[ic] + w[1]*cB[ic] + w[2]*n0[ic] + w[3]*n1[ic];
                accB += w[0]*n0[ic] + w[1]*n1[ic] + w[2]*n2[ic] + w[3]*n3[ic];
            }
            oA[oc] = ftanh(accA);
            oB[oc] = ftanh(accB);
        }

        // conv3: q0 = o3[2pp-1] (pp>0), q1 = o3[2pp]
        float q0[8], q1[8];
        if (pp > 0) {
#pragma unroll
            for (int oc = 0; oc < 8; ++oc) {
                float acc = cb3[oc];
#pragma unroll
                for (int ic = 0; ic < 8; ++ic)
                    acc += cw3[oc*16+ic*2]*o2p[ic] + cw3[oc*16+ic*2+1]*oA[ic];
                q0[oc] = ftanh(acc);
            }
        }
#pragma unroll
        for (int oc = 0; oc < 8; ++oc) {
            float acc = cb3[oc];
#pragma unroll
            for (int ic = 0; ic < 8; ++ic)
                acc += cw3[oc*16+ic*2]*oA[ic] + cw3[oc*16+ic*2+1]*oB[ic];
            q1[oc] = ftanh(acc);
        }

        // conv4 r=2pp-2 and r=2pp-1 (pp>0), each folded into t3 immediately
        if (pp > 0) {
            const int r0 = 2*pp - 2;
#pragma unroll
            for (int oc = 0; oc < 8; ++oc) {
                float acc = cb4[oc];
#pragma unroll
                for (int ic = 0; ic < 8; ++ic)
                    acc += cw4[oc*16+ic*2]*o3p[ic] + cw4[oc*16+ic*2+1]*q0[ic];
                float fv = ftanh(acc);
                const float* wr = &w3[(oc*4 + r0)*32];
#pragma unroll
                for (int j = 0; j < 32; ++j) t3[j] += fv * wr[j];
            }
#pragma unroll
            for (int oc = 0; oc < 8; ++oc) {
                float acc = cb4[oc];
#pragma unroll
                for (int ic = 0; ic < 8; ++ic)
                    acc += cw4[oc*16+ic*2]*q0[ic] + cw4[oc*16+ic*2+1]*q1[ic];
                float fv = ftanh(acc);
                const float* wr = &w3[(oc*4 + r0 + 1)*32];
#pragma unroll
                for (int j = 0; j < 32; ++j) t3[j] += fv * wr[j];
            }
        }

        // carries
#pragma unroll
        for (int ic = 0; ic < 8; ++ic) {
            cA[ic] = n2[ic]; cB[ic] = n3[ic];
            o2p[ic] = oB[ic]; o3p[ic] = q1[ic];
        }
    }

#pragma unroll
    for (int j = 0; j < 32; ++j) t3[j] = ftanh(t3[j]);

    // dense w4 (32,16) -> pre-norm code g
    float g[16];
#pragma unroll
    for (int j = 0; j < 16; ++j) g[j] = b4[j];
#pragma unroll
    for (int i = 0; i < 32; ++i) {
        float fv = t3[i];
#pragma unroll
        for (int j = 0; j < 16; ++j) g[j] += fv * w4[i*16+j];
    }

    {
        float4* gp = (float4*)(g_out + (size_t)row * 16);
        gp[0] = make_float4(g[0],g[1],g[2],g[3]);
        gp[1] = make_float4(g[4],g[5],g[6],g[7]);
        gp[2] = make_float4(g[8],g[9],g[10],g[11]);
        gp[3] = make_float4(g[12],g[13],g[14],g[15]);
    }

    // per-block column sums/sumsq (deterministic, no atomics)
    const int lane = tid & 63;
    const int wid = tid >> 6;
#pragma unroll
    for (int c = 0; c < 16; ++c) {
        float s = g[c];
        float q = g[c]*g[c];
#pragma unroll
        for (int off = 32; off > 0; off >>= 1) {
            s += __shfl_xor(s, off);
            q += __shfl_xor(q, off);
        }
        if (lane == c)      red[wid][c]      = s;
        if (lane == 16 + c) red[wid][16 + c] = q;
    }
    __syncthreads();
    if (tid < 32) {
        float t = red[0][tid] + red[1][tid] + red[2][tid] + red[3][tid];
        partials[blockIdx.x * 32 + tid] = t;
    }
}

__global__ __attribute__((amdgpu_flat_work_group_size(1024,1024)))
void stat_kernel(const float* __restrict__ partials,
                 float* __restrict__ muinv, int nblocks)
{
    __shared__ float lds[32][33];
    const int t = threadIdx.x;
    const int c = t & 31, chunk = t >> 5;   // 32 chunks x 32 cols
    // each chunk sums nblocks/32 = 64 rows; 4 independent accumulators
    float s0 = 0.0f, s1 = 0.0f, s2 = 0.0f, s3 = 0.0f;
    for (int k = 0; k < 64; k += 4) {
        s0 += partials[(chunk + (k    )*32)*32 + c];
        s1 += partials[(chunk + (k + 1)*32)*32 + c];
        s2 += partials[(chunk + (k + 2)*32)*32 + c];
        s3 += partials[(chunk + (k + 3)*32)*32 + c];
    }
    lds[chunk][c] = (s0 + s1) + (s2 + s3);
    __syncthreads();
    if (t < 32) {
        float tot = 0.0f;
#pragma unroll
        for (int k = 0; k < 32; ++k) tot += lds[k][t];
        lds[0][t] = tot;
    }
    __syncthreads();
    if (t < 16) {
        float mu  = lds[0][t] * (1.0f / (float)BATCH);
        float var = lds[0][16 + t] * (1.0f / (float)BATCH) - mu * mu;
        muinv[t]      = mu;
        muinv[16 + t] = rsqrtf(var + 1e-5f);
    }
}

__global__ __attribute__((amdgpu_flat_work_group_size(256,256), amdgpu_waves_per_eu(1,4)))
void dec_kernel(
    const float* __restrict__ g_in,
    const float* __restrict__ noise,
    const float* __restrict__ fading,
    const float* __restrict__ muinv,
    const float* __restrict__ dw1, const float* __restrict__ db1,
    const float* __restrict__ dw2, const float* __restrict__ db2,
    float* __restrict__ out)
{
    const int row = blockIdx.x * 256 + threadIdx.x;

    float enc[16];
    {
        const float4* gp = (const float4*)(g_in + (size_t)row * 16);
        float4 a0 = gp[0], a1 = gp[1], a2 = gp[2], a3 = gp[3];
        float g[16] = {a0.x,a0.y,a0.z,a0.w, a1.x,a1.y,a1.z,a1.w,
                       a2.x,a2.y,a2.z,a2.w, a3.x,a3.y,a3.z,a3.w};
#pragma unroll
        for (int c = 0; c < 16; ++c)
            enc[c] = (g[c] - muinv[c]) * muinv[16 + c];
    }

    float hr[3], hi[3];
    {
        const float2* fd = (const float2*)(fading + (size_t)row * 6);
        float2 f0 = fd[0], f1 = fd[1], f2 = fd[2];
        hr[0] = f0.x * INV_SQRT2; hi[0] = f0.y * INV_SQRT2;
        hr[1] = f1.x * INV_SQRT2; hi[1] = f1.y * INV_SQRT2;
        hr[2] = f2.x * INV_SQRT2; hi[2] = f2.y * INV_SQRT2;
    }

    // causal 3-tap complex conv + noise
    float cvec[16];
    {
        const float4* npz = (const float4*)(noise + (size_t)row * 16);
        float4 n0 = npz[0], n1 = npz[1], n2 = npz[2], n3 = npz[3];
        float nz[16] = {n0.x,n0.y,n0.z,n0.w, n1.x,n1.y,n1.z,n1.w,
                        n2.x,n2.y,n2.z,n2.w, n3.x,n3.y,n3.z,n3.w};
#pragma unroll
        for (int n = 0; n < 8; ++n) {
            float sr = 0.0f, si = 0.0f;
#pragma unroll
            for (int t = 0; t < 3; ++t) {
                if (n - t >= 0) {
                    float xr = enc[2*(n-t)], xi = enc[2*(n-t)+1];
                    sr += hr[t]*xr - hi[t]*xi;
                    si += hr[t]*xi + hi[t]*xr;
                }
            }
            cvec[2*n]   = sr + nz[2*n]   * NOISE_STD;
            cvec[2*n+1] = si + nz[2*n+1] * NOISE_STD;
        }
    }

    // decoder dense1 (16->32) + ELU
    float d[32];
#pragma unroll
    for (int j = 0; j < 32; ++j) d[j] = db1[j];
#pragma unroll
    for (int i = 0; i < 16; ++i) {
        float ci = cvec[i];
#pragma unroll
        for (int j = 0; j < 32; ++j) d[j] += ci * dw1[i*32+j];
    }
#pragma unroll
    for (int j = 0; j < 32; ++j) d[j] = eluf(d[j]);

    // decoder dense2 (32->16)
    float o[16];
#pragma unroll
    for (int j = 0; j < 16; ++j) o[j] = db2[j];
#pragma unroll
    for (int i = 0; i < 32; ++i) {
        float di = d[i];
#pragma unroll
        for (int j = 0; j < 16; ++j) o[j] += di * dw2[i*16+j];
    }

    float4* op = (float4*)(out + (size_t)row * 16);
    op[0] = make_float4(o[0],o[1],o[2],o[3]);
    op[1] = make_float4(o[4],o[5],o[6],o[7]);
    op[2] = make_float4(o[8],o[9],o[10],o[11]);
    op[3] = make_float4(o[12],o[13],o[14],o[15]);
}

extern "C" void kernel_launch(void* const* d_in, const int* in_sizes, int n_in,
                              void* d_out, int out_size, void* d_ws, size_t ws_size,
                              hipStream_t stream) {
    (void)in_sizes; (void)n_in; (void)out_size; (void)ws_size;

    const float* x      = (const float*)d_in[0];
    const float* noise  = (const float*)d_in[1];
    const float* fading = (const float*)d_in[2];
    const float* w1  = (const float*)d_in[3];
    const float* b1  = (const float*)d_in[4];
    const float* w2  = (const float*)d_in[5];
    const float* b2  = (const float*)d_in[6];
    const float* cw1 = (const float*)d_in[7];
    const float* cb1 = (const float*)d_in[8];
    const float* cw2 = (const float*)d_in[9];
    const float* cb2 = (const float*)d_in[10];
    const float* cw3 = (const float*)d_in[11];
    const float* cb3 = (const float*)d_in[12];
    const float* cw4 = (const float*)d_in[13];
    const float* cb4 = (const float*)d_in[14];
    const float* w3  = (const float*)d_in[15];
    const float* b3  = (const float*)d_in[16];
    const float* w4  = (const float*)d_in[17];
    const float* b4  = (const float*)d_in[18];
    const float* dw1 = (const float*)d_in[19];
    const float* db1 = (const float*)d_in[20];
    const float* dw2 = (const float*)d_in[21];
    const float* db2 = (const float*)d_in[22];
    float* outp = (float*)d_out;

    float* ws       = (float*)d_ws;
    float* muinv    = ws;                 // 32 floats
    float* partials = ws + 32;            // 2048*32 floats
    float* g        = ws + 32 + 2048*32;  // BATCH*16 floats

    const int nb = BATCH / 256;  // 2048

    enc_kernel<<<nb, 256, 0, stream>>>(x, w1,b1, w2,b2, cw1,cb1, cw2,cb2,
                                       cw3,cb3, cw4,cb4, w3,b3, w4,b4,
                                       g, partials);
    stat_kernel<<<1, 1024, 0, stream>>>(partials, muinv, nb);
    dec_kernel<<<nb, 256, 0, stream>>>(g, noise, fading, muinv,
                                       dw1,db1, dw2,db2, outp);
}

// Round 11
// 393.551 us; speedup vs baseline: 1.5942x; 1.1002x over previous
//
#include <hip/hip_runtime.h>

#define BATCH 524288
#define NOISE_STD 0.4466835921509630f
#define INV_SQRT2 0.7071067811865476f

__device__ __forceinline__ float eluf(float x) {
    return x > 0.0f ? x : __expf(x) - 1.0f;
}

// tanh(x) = 1 - 2/(exp(2x)+1); exp->inf gives 1, exp->0 gives -1 (no clamp needed)
__device__ __forceinline__ float ftanh(float x) {
    float t = __expf(2.0f * x);
    return 1.0f - __fdividef(2.0f, t + 1.0f);
}

// waves_per_eu(2,4): min 2 keeps the 256-VGPR budget that fixed R4's remat
// (R7: VGPR=112); max 4 lets the HW actually run 4 waves/EU (R7's (2,2)
// self-capped occupancy at 21% -> VALUBusy 69%, latency-bound).
__global__ __attribute__((amdgpu_flat_work_group_size(256,256), amdgpu_waves_per_eu(2,4)))
void enc_kernel(
    const float* __restrict__ x,
    const float* __restrict__ w1, const float* __restrict__ b1,
    const float* __restrict__ w2, const float* __restrict__ b2,
    const float* __restrict__ cw1, const float* __restrict__ cb1,
    const float* __restrict__ cw2, const float* __restrict__ cb2,
    const float* __restrict__ cw3, const float* __restrict__ cb3,
    const float* __restrict__ cw4, const float* __restrict__ cb4,
    const float* __restrict__ w3, const float* __restrict__ b3,
    const float* __restrict__ w4, const float* __restrict__ b4,
    float* __restrict__ g_out, float* __restrict__ partials)
{
    // stride 17 (odd) -> per-lane row reads hit 32 distinct banks, conflict-free.
    // Reused twice: (1) h2 activations for the conv loop, (2) g for the reduction.
    __shared__ float h2s[256][17];

    const int tid = threadIdx.x;
    const int row = blockIdx.x * 256 + tid;

    float v[16];
    {
        const float4* xp = (const float4*)(x + (size_t)row * 16);
        float4 a0 = xp[0], a1 = xp[1], a2 = xp[2], a3 = xp[3];
        v[0]=a0.x; v[1]=a0.y; v[2]=a0.z; v[3]=a0.w;
        v[4]=a1.x; v[5]=a1.y; v[6]=a1.z; v[7]=a1.w;
        v[8]=a2.x; v[9]=a2.y; v[10]=a2.z; v[11]=a2.w;
        v[12]=a3.x; v[13]=a3.y; v[14]=a3.z; v[15]=a3.w;
    }

    // dense1 + ELU
    float h1[16];
#pragma unroll
    for (int j = 0; j < 16; ++j) h1[j] = b1[j];
#pragma unroll
    for (int i = 0; i < 16; ++i) {
        float vi = v[i];
#pragma unroll
        for (int j = 0; j < 16; ++j) h1[j] += vi * w1[i*16+j];
    }
#pragma unroll
    for (int j = 0; j < 16; ++j) h1[j] = eluf(h1[j]);

    // dense2 + ELU -> h2 (regs) + LDS copy for runtime indexing in the conv pipeline
    float h2[16];
#pragma unroll
    for (int j = 0; j < 16; ++j) h2[j] = b2[j];
#pragma unroll
    for (int i = 0; i < 16; ++i) {
        float vi = h1[i];
#pragma unroll
        for (int j = 0; j < 16; ++j) h2[j] += vi * w2[i*16+j];
    }
#pragma unroll
    for (int j = 0; j < 16; ++j) {
        h2[j] = eluf(h2[j]);
        h2s[tid][j] = h2[j];
    }

    // ---- conv pipeline: 3 rolled iterations, 2 conv2 positions each ----
    float cA[8], cB[8];          // carry: c1[4pp], c1[4pp+1]
#pragma unroll
    for (int ic = 0; ic < 8; ++ic) {
        cA[ic] = ftanh(cb1[ic] + cw1[ic*2]*h2[0] + cw1[ic*2+1]*h2[1]);
        cB[ic] = ftanh(cb1[ic] + cw1[ic*2]*h2[1] + cw1[ic*2+1]*h2[2]);
    }
    float o2p[8], o3p[8];        // o2[2pp-1], o3[2pp-2] carries
#pragma unroll
    for (int ic = 0; ic < 8; ++ic) { o2p[ic] = 0.0f; o3p[ic] = 0.0f; }

    float t3[32];
#pragma unroll
    for (int j = 0; j < 32; ++j) t3[j] = b3[j];

#pragma unroll 1
    for (int pp = 0; pp < 3; ++pp) {
        const float* hrow = &h2s[tid][0];
        const int b4i = 4*pp;
        float e2 = hrow[b4i+2], e3 = hrow[b4i+3], e4 = hrow[b4i+4],
              e5 = hrow[b4i+5], e6 = hrow[b4i+6];

        // 4 new conv1 positions: c1[4pp+2 .. 4pp+5]
        float n0[8], n1[8], n2[8], n3[8];
#pragma unroll
        for (int ic = 0; ic < 8; ++ic) {
            float wa = cw1[ic*2], wb = cw1[ic*2+1], bb = cb1[ic];
            n0[ic] = ftanh(bb + wa*e2 + wb*e3);
            n1[ic] = ftanh(bb + wa*e3 + wb*e4);
            n2[ic] = ftanh(bb + wa*e4 + wb*e5);
            n3[ic] = ftanh(bb + wa*e5 + wb*e6);
        }

        // o2[2pp] from (cA,cB,n0,n1); o2[2pp+1] from (n0..n3)
        float oA[8], oB[8];
#pragma unroll
        for (int oc = 0; oc < 8; ++oc) {
            float accA = cb2[oc], accB = cb2[oc];
#pragma unroll
            for (int ic = 0; ic < 8; ++ic) {
                const float* w = &cw2[oc*32 + ic*4];
                accA += w[0]*cA[ic] + w[1]*cB[ic] + w[2]*n0[ic] + w[3]*n1[ic];
                accB += w[0]*n0[ic] + w[1]*n1[ic] + w[2]*n2[ic] + w[3]*n3[ic];
            }
            oA[oc] = ftanh(accA);
            oB[oc] = ftanh(accB);
        }

        // conv3: q0 = o3[2pp-1] (pp>0), q1 = o3[2pp]
        float q0[8], q1[8];
        if (pp > 0) {
#pragma unroll
            for (int oc = 0; oc < 8; ++oc) {
                float acc = cb3[oc];
#pragma unroll
                for (int ic = 0; ic < 8; ++ic)
                    acc += cw3[oc*16+ic*2]*o2p[ic] + cw3[oc*16+ic*2+1]*oA[ic];
                q0[oc] = ftanh(acc);
            }
        }
#pragma unroll
        for (int oc = 0; oc < 8; ++oc) {
            float acc = cb3[oc];
#pragma unroll
            for (int ic = 0; ic < 8; ++ic)
                acc += cw3[oc*16+ic*2]*oA[ic] + cw3[oc*16+ic*2+1]*oB[ic];
            q1[oc] = ftanh(acc);
        }

        // conv4 r=2pp-2 and r=2pp-1 (pp>0), folded into t3 immediately
        if (pp > 0) {
            const int r0 = 2*pp - 2;
#pragma unroll
            for (int oc = 0; oc < 8; ++oc) {
                float acc = cb4[oc];
#pragma unroll
                for (int ic = 0; ic < 8; ++ic)
                    acc += cw4[oc*16+ic*2]*o3p[ic] + cw4[oc*16+ic*2+1]*q0[ic];
                float fv = ftanh(acc);
                const float* wr = &w3[(oc*4 + r0)*32];
#pragma unroll
                for (int j = 0; j < 32; ++j) t3[j] += fv * wr[j];
            }
#pragma unroll
            for (int oc = 0; oc < 8; ++oc) {
                float acc = cb4[oc];
#pragma unroll
                for (int ic = 0; ic < 8; ++ic)
                    acc += cw4[oc*16+ic*2]*q0[ic] + cw4[oc*16+ic*2+1]*q1[ic];
                float fv = ftanh(acc);
                const float* wr = &w3[(oc*4 + r0 + 1)*32];
#pragma unroll
                for (int j = 0; j < 32; ++j) t3[j] += fv * wr[j];
            }
        }

        // carries
#pragma unroll
        for (int ic = 0; ic < 8; ++ic) {
            cA[ic] = n2[ic]; cB[ic] = n3[ic];
            o2p[ic] = oB[ic]; o3p[ic] = q1[ic];
        }
    }

#pragma unroll
    for (int j = 0; j < 32; ++j) t3[j] = ftanh(t3[j]);

    // dense w4 (32,16) -> pre-norm code g
    float g[16];
#pragma unroll
    for (int j = 0; j < 16; ++j) g[j] = b4[j];
#pragma unroll
    for (int i = 0; i < 32; ++i) {
        float fv = t3[i];
#pragma unroll
        for (int j = 0; j < 16; ++j) g[j] += fv * w4[i*16+j];
    }

    {
        float4* gp = (float4*)(g_out + (size_t)row * 16);
        gp[0] = make_float4(g[0],g[1],g[2],g[3]);
        gp[1] = make_float4(g[4],g[5],g[6],g[7]);
        gp[2] = make_float4(g[8],g[9],g[10],g[11]);
        gp[3] = make_float4(g[12],g[13],g[14],g[15]);
    }

    // ---- column sums/sumsq via LDS transpose (replaces 192 bpermutes/thread) ----
    // reuse h2s (conv loop is done); barrier orders the overwrite.
    __syncthreads();
#pragma unroll
    for (int c = 0; c < 16; ++c) h2s[tid][c] = g[c];
    __syncthreads();
    if (tid < 64) {
        const int c = tid & 15, q = tid >> 4;   // 4 quarters x 16 cols
        float s = 0.0f, ss = 0.0f;
        const int r0 = q * 64;
        for (int r_ = 0; r_ < 64; ++r_) {
            float val = h2s[r0 + r_][c];
            s += val;
            ss += val * val;
        }
        // combine quarters: lanes with equal c differ in bits 4..5
        s  += __shfl_xor(s, 16);  s  += __shfl_xor(s, 32);
        ss += __shfl_xor(ss, 16); ss += __shfl_xor(ss, 32);
        if (q == 0) {
            partials[blockIdx.x * 32 + c]      = s;
            partials[blockIdx.x * 32 + 16 + c] = ss;
        }
    }
}

__global__ __attribute__((amdgpu_flat_work_group_size(1024,1024)))
void stat_kernel(const float* __restrict__ partials,
                 float* __restrict__ muinv, int nblocks)
{
    __shared__ float lds[32][33];
    const int t = threadIdx.x;
    const int c = t & 31, chunk = t >> 5;   // 32 chunks x 32 cols
    float s0 = 0.0f, s1 = 0.0f, s2 = 0.0f, s3 = 0.0f;
    for (int k = 0; k < 64; k += 4) {
        s0 += partials[(chunk + (k    )*32)*32 + c];
        s1 += partials[(chunk + (k + 1)*32)*32 + c];
        s2 += partials[(chunk + (k + 2)*32)*32 + c];
        s3 += partials[(chunk + (k + 3)*32)*32 + c];
    }
    lds[chunk][c] = (s0 + s1) + (s2 + s3);
    __syncthreads();
    if (t < 32) {
        float tot = 0.0f;
#pragma unroll
        for (int k = 0; k < 32; ++k) tot += lds[k][t];
        lds[0][t] = tot;
    }
    __syncthreads();
    if (t < 16) {
        float mu  = lds[0][t] * (1.0f / (float)BATCH);
        float var = lds[0][16 + t] * (1.0f / (float)BATCH) - mu * mu;
        muinv[t]      = mu;
        muinv[16 + t] = rsqrtf(var + 1e-5f);
    }
}

__global__ __attribute__((amdgpu_flat_work_group_size(256,256), amdgpu_waves_per_eu(2,8)))
void dec_kernel(
    const float* __restrict__ g_in,
    const float* __restrict__ noise,
    const float* __restrict__ fading,
    const float* __restrict__ muinv,
    const float* __restrict__ dw1, const float* __restrict__ db1,
    const float* __restrict__ dw2, const float* __restrict__ db2,
    float* __restrict__ out)
{
    const int row = blockIdx.x * 256 + threadIdx.x;

    float enc[16];
    {
        const float4* gp = (const float4*)(g_in + (size_t)row * 16);
        float4 a0 = gp[0], a1 = gp[1], a2 = gp[2], a3 = gp[3];
        float g[16] = {a0.x,a0.y,a0.z,a0.w, a1.x,a1.y,a1.z,a1.w,
                       a2.x,a2.y,a2.z,a2.w, a3.x,a3.y,a3.z,a3.w};
#pragma unroll
        for (int c = 0; c < 16; ++c)
            enc[c] = (g[c] - muinv[c]) * muinv[16 + c];
    }

    float hr[3], hi[3];
    {
        const float2* fd = (const float2*)(fading + (size_t)row * 6);
        float2 f0 = fd[0], f1 = fd[1], f2 = fd[2];
        hr[0] = f0.x * INV_SQRT2; hi[0] = f0.y * INV_SQRT2;
        hr[1] = f1.x * INV_SQRT2; hi[1] = f1.y * INV_SQRT2;
        hr[2] = f2.x * INV_SQRT2; hi[2] = f2.y * INV_SQRT2;
    }

    // causal 3-tap complex conv + noise
    float cvec[16];
    {
        const float4* npz = (const float4*)(noise + (size_t)row * 16);
        float4 n0 = npz[0], n1 = npz[1], n2 = npz[2], n3 = npz[3];
        float nz[16] = {n0.x,n0.y,n0.z,n0.w, n1.x,n1.y,n1.z,n1.w,
                        n2.x,n2.y,n2.z,n2.w, n3.x,n3.y,n3.z,n3.w};
#pragma unroll
        for (int n = 0; n < 8; ++n) {
            float sr = 0.0f, si = 0.0f;
#pragma unroll
            for (int t = 0; t < 3; ++t) {
                if (n - t >= 0) {
                    float xr = enc[2*(n-t)], xi = enc[2*(n-t)+1];
                    sr += hr[t]*xr - hi[t]*xi;
                    si += hr[t]*xi + hi[t]*xr;
                }
            }
            cvec[2*n]   = sr + nz[2*n]   * NOISE_STD;
            cvec[2*n+1] = si + nz[2*n+1] * NOISE_STD;
        }
    }

    // decoder dense1 (16->32) + ELU
    float d[32];
#pragma unroll
    for (int j = 0; j < 32; ++j) d[j] = db1[j];
#pragma unroll
    for (int i = 0; i < 16; ++i) {
        float ci = cvec[i];
#pragma unroll
        for (int j = 0; j < 32; ++j) d[j] += ci * dw1[i*32+j];
    }
#pragma unroll
    for (int j = 0; j < 32; ++j) d[j] = eluf(d[j]);

    // decoder dense2 (32->16)
    float o[16];
#pragma unroll
    for (int j = 0; j < 16; ++j) o[j] = db2[j];
#pragma unroll
    for (int i = 0; i < 32; ++i) {
        float di = d[i];
#pragma unroll
        for (int j = 0; j < 16; ++j) o[j] += di * dw2[i*16+j];
    }

    float4* op = (float4*)(out + (size_t)row * 16);
    op[0] = make_float4(o[0],o[1],o[2],o[3]);
    op[1] = make_float4(o[4],o[5],o[6],o[7]);
    op[2] = make_float4(o[8],o[9],o[10],o[11]);
    op[3] = make_float4(o[12],o[13],o[14],o[15]);
}

extern "C" void kernel_launch(void* const* d_in, const int* in_sizes, int n_in,
                              void* d_out, int out_size, void* d_ws, size_t ws_size,
                              hipStream_t stream) {
    (void)in_sizes; (void)n_in; (void)out_size; (void)ws_size;

    const float* x      = (const float*)d_in[0];
    const float* noise  = (const float*)d_in[1];
    const float* fading = (const float*)d_in[2];
    const float* w1  = (const float*)d_in[3];
    const float* b1  = (const float*)d_in[4];
    const float* w2  = (const float*)d_in[5];
    const float* b2  = (const float*)d_in[6];
    const float* cw1 = (const float*)d_in[7];
    const float* cb1 = (const float*)d_in[8];
    const float* cw2 = (const float*)d_in[9];
    const float* cb2 = (const float*)d_in[10];
    const float* cw3 = (const float*)d_in[11];
    const float* cb3 = (const float*)d_in[12];
    const float* cw4 = (const float*)d_in[13];
    const float* cb4 = (const float*)d_in[14];
    const float* w3  = (const float*)d_in[15];
    const float* b3  = (const float*)d_in[16];
    const float* w4  = (const float*)d_in[17];
    const float* b4  = (const float*)d_in[18];
    const float* dw1 = (const float*)d_in[19];
    const float* db1 = (const float*)d_in[20];
    const float* dw2 = (const float*)d_in[21];
    const float* db2 = (const float*)d_in[22];
    float* outp = (float*)d_out;

    float* ws       = (float*)d_ws;
    float* muinv    = ws;                 // 32 floats
    float* partials = ws + 32;            // 2048*32 floats
    float* g        = ws + 32 + 2048*32;  // BATCH*16 floats

    const int nb = BATCH / 256;  // 2048

    enc_kernel<<<nb, 256, 0, stream>>>(x, w1,b1, w2,b2, cw1,cb1, cw2,cb2,
                                       cw3,cb3, cw4,cb4, w3,b3, w4,b4,
                                       g, partials);
    stat_kernel<<<1, 1024, 0, stream>>>(partials, muinv, nb);
    dec_kernel<<<nb, 256, 0, stream>>>(g, noise, fading, muinv,
                                       dw1,db1, dw2,db2, outp);
}